// Round 2
// baseline (804.784 us; speedup 1.0000x reference)
//
#include <hip/hip_runtime.h>

#define HIDDEN 64

// =====================  CSR-build kernels  =====================

__global__ __launch_bounds__(256) void hist_kernel(const int* __restrict__ ei, int* __restrict__ cnt,
                                                   int E) {
    int i = blockIdx.x * blockDim.x + threadIdx.x;
    int stride = gridDim.x * blockDim.x;
    for (; i < E; i += stride) atomicAdd(&cnt[ei[E + i]], 1);
}

// Block-tile exclusive scan: each block scans a tile of 1024 ints in place,
// writes tile total to partial[].
__global__ __launch_bounds__(256) void scan1_kernel(int* __restrict__ cnt, int* __restrict__ partial,
                                                    int N) {
    __shared__ int s[256];
    const int t = threadIdx.x;
    const int base = blockIdx.x * 1024 + t * 4;
    int v0 = (base + 0 < N) ? cnt[base + 0] : 0;
    int v1 = (base + 1 < N) ? cnt[base + 1] : 0;
    int v2 = (base + 2 < N) ? cnt[base + 2] : 0;
    int v3 = (base + 3 < N) ? cnt[base + 3] : 0;
    const int mysum = v0 + v1 + v2 + v3;
    s[t] = mysum;
    __syncthreads();
    for (int d = 1; d < 256; d <<= 1) {
        int u = (t >= d) ? s[t - d] : 0;
        __syncthreads();
        s[t] += u;
        __syncthreads();
    }
    const int excl = s[t] - mysum;  // exclusive offset of this thread within block
    if (base + 0 < N) cnt[base + 0] = excl;
    if (base + 1 < N) cnt[base + 1] = excl + v0;
    if (base + 2 < N) cnt[base + 2] = excl + v0 + v1;
    if (base + 3 < N) cnt[base + 3] = excl + v0 + v1 + v2;
    if (t == 255) partial[blockIdx.x] = s[255];
}

// Single-block exclusive scan of block partials (nb <= 256).
__global__ __launch_bounds__(256) void scan2_kernel(int* __restrict__ partial, int nb) {
    __shared__ int s[256];
    const int t = threadIdx.x;
    const int mysum = (t < nb) ? partial[t] : 0;
    s[t] = mysum;
    __syncthreads();
    for (int d = 1; d < 256; d <<= 1) {
        int u = (t >= d) ? s[t - d] : 0;
        __syncthreads();
        s[t] += u;
        __syncthreads();
    }
    if (t < nb) partial[t] = s[t] - mysum;
}

// Add block offsets; init cursors; set off[N] = E.
__global__ __launch_bounds__(256) void scan3_kernel(int* __restrict__ off, int* __restrict__ cur,
                                                    const int* __restrict__ partial, int N, int E) {
    int i = blockIdx.x * blockDim.x + threadIdx.x;
    if (i < N) {
        const int o = off[i] + partial[i >> 10];
        off[i] = o;
        cur[i] = o;
    }
    if (i == 0) off[N] = E;
}

__global__ __launch_bounds__(256) void scatter_kernel(const int* __restrict__ ei, int* __restrict__ cur,
                                                      int2* __restrict__ pairs, int E) {
    int i = blockIdx.x * blockDim.x + threadIdx.x;
    int stride = gridDim.x * blockDim.x;
    for (; i < E; i += stride) {
        const int src = ei[i];
        const int dst = ei[E + i];
        const int slot = atomicAdd(&cur[dst], 1);
        pairs[slot] = make_int2(src, i);
    }
}

// =====================  fused gather + MLP  =====================
// One wave per node: registers accumulate agg; MLP via LDS weights + shfl.
__global__ __launch_bounds__(256) void gine_node_kernel(
    const float* __restrict__ x, const int* __restrict__ off, const int2* __restrict__ pairs,
    const float4* __restrict__ ea, const float* __restrict__ We, const float* __restrict__ be,
    const float* __restrict__ W1, const float* __restrict__ b1, const float* __restrict__ W2,
    const float* __restrict__ b2, float* __restrict__ out, int N) {
    __shared__ float sW1[64 * 64];
    __shared__ float sW2[64 * 64];
    __shared__ float sb[128];
    for (int i = threadIdx.x; i < 64 * 64; i += blockDim.x) {
        sW1[i] = W1[i];
        sW2[i] = W2[i];
    }
    if (threadIdx.x < 64) {
        sb[threadIdx.x] = b1[threadIdx.x];
        sb[64 + threadIdx.x] = b2[threadIdx.x];
    }
    const int lane = threadIdx.x & 63;
    const float w0 = We[lane];
    const float w1 = We[64 + lane];
    const float w2 = We[128 + lane];
    const float w3 = We[192 + lane];
    const float bb = be[lane];
    __syncthreads();
    int wave = (blockIdx.x * blockDim.x + threadIdx.x) >> 6;
    const int nw = (gridDim.x * blockDim.x) >> 6;
    for (int n = wave; n < N; n += nw) {
        const int s0 = off[n];
        const int s1 = off[n + 1];
        float acc = x[n * HIDDEN + lane];
        for (int s = s0; s < s1; ++s) {
            const int2 p = pairs[s];
            const float4 a = ea[p.y];
            float m = x[p.x * HIDDEN + lane] + (bb + a.x * w0 + a.y * w1 + a.z * w2 + a.w * w3);
            acc += fmaxf(m, 0.0f);
        }
        // MLP: out = relu(h@W1+b1)@W2+b2
        float t = sb[lane];
#pragma unroll
        for (int k = 0; k < 64; ++k) t = fmaf(__shfl(acc, k), sW1[k * 64 + lane], t);
        t = fmaxf(t, 0.0f);
        float o = sb[64 + lane];
#pragma unroll
        for (int k = 0; k < 64; ++k) o = fmaf(__shfl(t, k), sW2[k * 64 + lane], o);
        out[n * HIDDEN + lane] = o;
    }
}

// =====================  fallback (ws too small): round-1 atomic path =====================
__global__ __launch_bounds__(256) void gine_copy_kernel(const float4* __restrict__ x,
                                                        float4* __restrict__ out, int n4) {
    int i = blockIdx.x * blockDim.x + threadIdx.x;
    int stride = gridDim.x * blockDim.x;
    for (; i < n4; i += stride) out[i] = x[i];
}

__global__ __launch_bounds__(256) void gine_edge_kernel(const float* __restrict__ x,
                                                        const int* __restrict__ ei,
                                                        const float4* __restrict__ ea,
                                                        const float* __restrict__ We,
                                                        const float* __restrict__ be,
                                                        float* __restrict__ out, int E) {
    const int lane = threadIdx.x & 63;
    const float w0 = We[lane];
    const float w1 = We[64 + lane];
    const float w2 = We[128 + lane];
    const float w3 = We[192 + lane];
    const float bb = be[lane];
    int wave = (blockIdx.x * blockDim.x + threadIdx.x) >> 6;
    const int nw = (gridDim.x * blockDim.x) >> 6;
    for (int e = wave; e < E; e += nw) {
        const int src = ei[e];
        const int dst = ei[E + e];
        const float4 a = ea[e];
        float m = x[src * HIDDEN + lane] + (bb + a.x * w0 + a.y * w1 + a.z * w2 + a.w * w3);
        m = fmaxf(m, 0.0f);
        atomicAdd(out + dst * HIDDEN + lane, m);
    }
}

__global__ __launch_bounds__(256) void gine_mlp_kernel(const float* __restrict__ W1,
                                                       const float* __restrict__ b1,
                                                       const float* __restrict__ W2,
                                                       const float* __restrict__ b2,
                                                       float* __restrict__ out, int N) {
    __shared__ float sW1[64 * 64];
    __shared__ float sW2[64 * 64];
    __shared__ float sb1[64], sb2[64];
    for (int i = threadIdx.x; i < 64 * 64; i += blockDim.x) {
        sW1[i] = W1[i];
        sW2[i] = W2[i];
    }
    if (threadIdx.x < 64) {
        sb1[threadIdx.x] = b1[threadIdx.x];
        sb2[threadIdx.x] = b2[threadIdx.x];
    }
    __syncthreads();
    const int lane = threadIdx.x & 63;
    int wave = (blockIdx.x * blockDim.x + threadIdx.x) >> 6;
    const int nw = (gridDim.x * blockDim.x) >> 6;
    for (int n = wave; n < N; n += nw) {
        const float h = out[n * HIDDEN + lane];
        float t = sb1[lane];
#pragma unroll
        for (int k = 0; k < 64; ++k) t = fmaf(__shfl(h, k), sW1[k * 64 + lane], t);
        t = fmaxf(t, 0.0f);
        float o = sb2[lane];
#pragma unroll
        for (int k = 0; k < 64; ++k) o = fmaf(__shfl(t, k), sW2[k * 64 + lane], o);
        out[n * HIDDEN + lane] = o;
    }
}

extern "C" void kernel_launch(void* const* d_in, const int* in_sizes, int n_in,
                              void* d_out, int out_size, void* d_ws, size_t ws_size,
                              hipStream_t stream) {
    const float* x  = (const float*)d_in[0];
    const int*   ei = (const int*)d_in[1];
    const float* ea = (const float*)d_in[2];
    const float* We = (const float*)d_in[3];
    const float* be = (const float*)d_in[4];
    const float* W1 = (const float*)d_in[5];
    const float* b1 = (const float*)d_in[6];
    const float* W2 = (const float*)d_in[7];
    const float* b2 = (const float*)d_in[8];
    float* out = (float*)d_out;

    const int N = in_sizes[0] / HIDDEN;   // 100000
    const int E = in_sizes[1] / 2;        // 1600000

    // Workspace layout
    const size_t off_bytes  = (size_t)(N + 1) * 4;
    size_t p = 0;
    const size_t off_ofs  = p; p += (off_bytes + 255) & ~(size_t)255;
    const size_t cur_ofs  = p; p += ((size_t)N * 4 + 255) & ~(size_t)255;
    const size_t part_ofs = p; p += 512 * 4;
    const size_t pair_ofs = p; p += (size_t)E * 8;
    const size_t need = p;

    if (ws_size < need) {
        // Fallback: atomic scatter path (round-1, known-correct)
        gine_copy_kernel<<<2048, 256, 0, stream>>>((const float4*)x, (float4*)out,
                                                   N * (HIDDEN / 4));
        gine_edge_kernel<<<2048, 256, 0, stream>>>(x, ei, (const float4*)ea, We, be, out, E);
        gine_mlp_kernel<<<2048, 256, 0, stream>>>(W1, b1, W2, b2, out, N);
        return;
    }

    char* ws = (char*)d_ws;
    int*  off   = (int*)(ws + off_ofs);
    int*  cur   = (int*)(ws + cur_ofs);
    int*  part  = (int*)(ws + part_ofs);
    int2* pairs = (int2*)(ws + pair_ofs);

    const int nb_scan = (N + 1023) / 1024;  // <= 256 for N <= 262144

    hipMemsetAsync(off, 0, off_bytes, stream);
    hist_kernel<<<2048, 256, 0, stream>>>(ei, off, E);
    scan1_kernel<<<nb_scan, 256, 0, stream>>>(off, part, N);
    scan2_kernel<<<1, 256, 0, stream>>>(part, nb_scan);
    scan3_kernel<<<(N + 255) / 256, 256, 0, stream>>>(off, cur, part, N, E);
    scatter_kernel<<<2048, 256, 0, stream>>>(ei, cur, pairs, E);
    gine_node_kernel<<<2048, 256, 0, stream>>>(x, off, pairs, (const float4*)ea, We, be,
                                               W1, b1, W2, b2, out, N);
}

// Round 3
// 372.764 us; speedup vs baseline: 2.1590x; 2.1590x over previous
//
#include <hip/hip_runtime.h>

#define HIDDEN 64

__device__ __forceinline__ float lane_bcast(float v, int l) {
    return __uint_as_float(__builtin_amdgcn_readlane(__float_as_uint(v), l));
}

// =====================  CSR-build kernels  =====================

__global__ __launch_bounds__(256) void hist_kernel(const int* __restrict__ ei, int* __restrict__ cnt,
                                                   int E) {
    int i = blockIdx.x * blockDim.x + threadIdx.x;
    int stride = gridDim.x * blockDim.x;
    for (; i < E; i += stride) atomicAdd(&cnt[ei[E + i]], 1);
}

__global__ __launch_bounds__(256) void scan1_kernel(int* __restrict__ cnt, int* __restrict__ partial,
                                                    int N) {
    __shared__ int s[256];
    const int t = threadIdx.x;
    const int base = blockIdx.x * 1024 + t * 4;
    int v0 = (base + 0 < N) ? cnt[base + 0] : 0;
    int v1 = (base + 1 < N) ? cnt[base + 1] : 0;
    int v2 = (base + 2 < N) ? cnt[base + 2] : 0;
    int v3 = (base + 3 < N) ? cnt[base + 3] : 0;
    const int mysum = v0 + v1 + v2 + v3;
    s[t] = mysum;
    __syncthreads();
    for (int d = 1; d < 256; d <<= 1) {
        int u = (t >= d) ? s[t - d] : 0;
        __syncthreads();
        s[t] += u;
        __syncthreads();
    }
    const int excl = s[t] - mysum;
    if (base + 0 < N) cnt[base + 0] = excl;
    if (base + 1 < N) cnt[base + 1] = excl + v0;
    if (base + 2 < N) cnt[base + 2] = excl + v0 + v1;
    if (base + 3 < N) cnt[base + 3] = excl + v0 + v1 + v2;
    if (t == 255) partial[blockIdx.x] = s[255];
}

__global__ __launch_bounds__(256) void scan2_kernel(int* __restrict__ partial, int nb) {
    __shared__ int s[256];
    const int t = threadIdx.x;
    const int mysum = (t < nb) ? partial[t] : 0;
    s[t] = mysum;
    __syncthreads();
    for (int d = 1; d < 256; d <<= 1) {
        int u = (t >= d) ? s[t - d] : 0;
        __syncthreads();
        s[t] += u;
        __syncthreads();
    }
    if (t < nb) partial[t] = s[t] - mysum;
}

__global__ __launch_bounds__(256) void scan3_kernel(int* __restrict__ off, int* __restrict__ cur,
                                                    const int* __restrict__ partial, int N, int E) {
    int i = blockIdx.x * blockDim.x + threadIdx.x;
    if (i < N) {
        const int o = off[i] + partial[i >> 10];
        off[i] = o;
        cur[i] = o;
    }
    if (i == 0) off[N] = E;
}

__global__ __launch_bounds__(256) void scatter_kernel(const int* __restrict__ ei, int* __restrict__ cur,
                                                      int2* __restrict__ pairs, int E) {
    int i = blockIdx.x * blockDim.x + threadIdx.x;
    int stride = gridDim.x * blockDim.x;
    for (; i < E; i += stride) {
        const int src = ei[i];
        const int dst = ei[E + i];
        const int slot = atomicAdd(&cur[dst], 1);
        pairs[slot] = make_int2(src, i);
    }
}

// =====================  gather (no MLP, no LDS, 4-way ILP)  =====================
// One wave per node; writes h = x[n] + sum relu(x[src]+eproj) to hbuf.
__global__ __launch_bounds__(256) void gather_kernel(
    const float* __restrict__ x, const int* __restrict__ off, const int2* __restrict__ pairs,
    const float4* __restrict__ ea, const float* __restrict__ We, const float* __restrict__ be,
    float* __restrict__ hbuf, int N) {
    const int lane = threadIdx.x & 63;
    const float w0 = We[lane];
    const float w1 = We[64 + lane];
    const float w2 = We[128 + lane];
    const float w3 = We[192 + lane];
    const float bb = be[lane];
    int wave = (blockIdx.x * blockDim.x + threadIdx.x) >> 6;
    const int nw = (gridDim.x * blockDim.x) >> 6;
    for (int n = wave; n < N; n += nw) {
        const int s0 = off[n];
        const int s1 = off[n + 1];
        float acc = x[(size_t)n * HIDDEN + lane];
        int s = s0;
        for (; s + 4 <= s1; s += 4) {
            const int2 p0 = pairs[s + 0];
            const int2 p1 = pairs[s + 1];
            const int2 p2 = pairs[s + 2];
            const int2 p3 = pairs[s + 3];
            const float4 a0 = ea[p0.y];
            const float4 a1 = ea[p1.y];
            const float4 a2 = ea[p2.y];
            const float4 a3 = ea[p3.y];
            const float x0 = x[(size_t)p0.x * HIDDEN + lane];
            const float x1 = x[(size_t)p1.x * HIDDEN + lane];
            const float x2 = x[(size_t)p2.x * HIDDEN + lane];
            const float x3 = x[(size_t)p3.x * HIDDEN + lane];
            acc += fmaxf(x0 + (bb + a0.x * w0 + a0.y * w1 + a0.z * w2 + a0.w * w3), 0.0f);
            acc += fmaxf(x1 + (bb + a1.x * w0 + a1.y * w1 + a1.z * w2 + a1.w * w3), 0.0f);
            acc += fmaxf(x2 + (bb + a2.x * w0 + a2.y * w1 + a2.z * w2 + a2.w * w3), 0.0f);
            acc += fmaxf(x3 + (bb + a3.x * w0 + a3.y * w1 + a3.z * w2 + a3.w * w3), 0.0f);
        }
        for (; s < s1; ++s) {
            const int2 p = pairs[s];
            const float4 a = ea[p.y];
            const float xv = x[(size_t)p.x * HIDDEN + lane];
            acc += fmaxf(xv + (bb + a.x * w0 + a.y * w1 + a.z * w2 + a.w * w3), 0.0f);
        }
        hbuf[(size_t)n * HIDDEN + lane] = acc;
    }
}

// =====================  MLP via readlane broadcast (zero DS)  =====================
// One wave per node; W1/W2 columns live in registers. Safe for hin == out.
__global__ __launch_bounds__(256) void mlp_kernel(const float* __restrict__ hin,
                                                  const float* __restrict__ W1,
                                                  const float* __restrict__ b1,
                                                  const float* __restrict__ W2,
                                                  const float* __restrict__ b2,
                                                  float* __restrict__ out, int N) {
    const int lane = threadIdx.x & 63;
    float w1c[64], w2c[64];
#pragma unroll
    for (int k = 0; k < 64; ++k) w1c[k] = W1[k * 64 + lane];
#pragma unroll
    for (int k = 0; k < 64; ++k) w2c[k] = W2[k * 64 + lane];
    const float bb1 = b1[lane];
    const float bb2 = b2[lane];
    int wave = (blockIdx.x * blockDim.x + threadIdx.x) >> 6;
    const int nw = (gridDim.x * blockDim.x) >> 6;
    for (int n = wave; n < N; n += nw) {
        const float h = hin[(size_t)n * HIDDEN + lane];
        float t0 = bb1, t1 = 0.0f;
#pragma unroll
        for (int k = 0; k < 64; k += 2) {
            t0 = fmaf(lane_bcast(h, k), w1c[k], t0);
            t1 = fmaf(lane_bcast(h, k + 1), w1c[k + 1], t1);
        }
        const float t = fmaxf(t0 + t1, 0.0f);
        float o0 = bb2, o1 = 0.0f;
#pragma unroll
        for (int k = 0; k < 64; k += 2) {
            o0 = fmaf(lane_bcast(t, k), w2c[k], o0);
            o1 = fmaf(lane_bcast(t, k + 1), w2c[k + 1], o1);
        }
        out[(size_t)n * HIDDEN + lane] = o0 + o1;
    }
}

// =====================  fallback (ws too small): atomic path  =====================
__global__ __launch_bounds__(256) void gine_copy_kernel(const float4* __restrict__ x,
                                                        float4* __restrict__ out, int n4) {
    int i = blockIdx.x * blockDim.x + threadIdx.x;
    int stride = gridDim.x * blockDim.x;
    for (; i < n4; i += stride) out[i] = x[i];
}

__global__ __launch_bounds__(256) void gine_edge_kernel(const float* __restrict__ x,
                                                        const int* __restrict__ ei,
                                                        const float4* __restrict__ ea,
                                                        const float* __restrict__ We,
                                                        const float* __restrict__ be,
                                                        float* __restrict__ out, int E) {
    const int lane = threadIdx.x & 63;
    const float w0 = We[lane];
    const float w1 = We[64 + lane];
    const float w2 = We[128 + lane];
    const float w3 = We[192 + lane];
    const float bb = be[lane];
    int wave = (blockIdx.x * blockDim.x + threadIdx.x) >> 6;
    const int nw = (gridDim.x * blockDim.x) >> 6;
    for (int e = wave; e < E; e += nw) {
        const int src = ei[e];
        const int dst = ei[E + e];
        const float4 a = ea[e];
        float m = x[src * HIDDEN + lane] + (bb + a.x * w0 + a.y * w1 + a.z * w2 + a.w * w3);
        m = fmaxf(m, 0.0f);
        atomicAdd(out + dst * HIDDEN + lane, m);
    }
}

extern "C" void kernel_launch(void* const* d_in, const int* in_sizes, int n_in,
                              void* d_out, int out_size, void* d_ws, size_t ws_size,
                              hipStream_t stream) {
    const float* x  = (const float*)d_in[0];
    const int*   ei = (const int*)d_in[1];
    const float* ea = (const float*)d_in[2];
    const float* We = (const float*)d_in[3];
    const float* be = (const float*)d_in[4];
    const float* W1 = (const float*)d_in[5];
    const float* b1 = (const float*)d_in[6];
    const float* W2 = (const float*)d_in[7];
    const float* b2 = (const float*)d_in[8];
    float* out = (float*)d_out;

    const int N = in_sizes[0] / HIDDEN;   // 100000
    const int E = in_sizes[1] / 2;        // 1600000

    // Workspace layout
    const size_t off_bytes = (size_t)(N + 1) * 4;
    size_t p = 0;
    const size_t off_ofs  = p; p += (off_bytes + 255) & ~(size_t)255;
    const size_t cur_ofs  = p; p += ((size_t)N * 4 + 255) & ~(size_t)255;
    const size_t part_ofs = p; p += 512 * 4;
    const size_t pair_ofs = p; p += (size_t)E * 8;
    const size_t h_ofs    = p; p += (size_t)N * HIDDEN * 4;
    const size_t need = p;

    if (ws_size < need) {
        gine_copy_kernel<<<2048, 256, 0, stream>>>((const float4*)x, (float4*)out,
                                                   N * (HIDDEN / 4));
        gine_edge_kernel<<<2048, 256, 0, stream>>>(x, ei, (const float4*)ea, We, be, out, E);
        mlp_kernel<<<2048, 256, 0, stream>>>(out, W1, b1, W2, b2, out, N);
        return;
    }

    char* ws = (char*)d_ws;
    int*   off   = (int*)(ws + off_ofs);
    int*   cur   = (int*)(ws + cur_ofs);
    int*   part  = (int*)(ws + part_ofs);
    int2*  pairs = (int2*)(ws + pair_ofs);
    float* hbuf  = (float*)(ws + h_ofs);

    const int nb_scan = (N + 1023) / 1024;  // <= 256 for N <= 262144

    hipMemsetAsync(off, 0, off_bytes, stream);
    hist_kernel<<<2048, 256, 0, stream>>>(ei, off, E);
    scan1_kernel<<<nb_scan, 256, 0, stream>>>(off, part, N);
    scan2_kernel<<<1, 256, 0, stream>>>(part, nb_scan);
    scan3_kernel<<<(N + 255) / 256, 256, 0, stream>>>(off, cur, part, N, E);
    scatter_kernel<<<2048, 256, 0, stream>>>(ei, cur, pairs, E);
    gather_kernel<<<2048, 256, 0, stream>>>(x, off, pairs, (const float4*)ea, We, be, hbuf, N);
    mlp_kernel<<<2048, 256, 0, stream>>>(hbuf, W1, b1, W2, b2, out, N);
}